// Round 11
// baseline (186.528 us; speedup 1.0000x reference)
//
#include <hip/hip_runtime.h>
#include <stdint.h>

typedef __attribute__((ext_vector_type(8))) short short8;
typedef __attribute__((ext_vector_type(4))) float f32x4;

#define QSCALE 0.18033688011112043f   // (1/sqrt(64)) * log2(e), folded into W_q/b_q

__device__ __forceinline__ unsigned short f2b(float f) {
  union { float f; uint32_t u; } v; v.f = f;
  uint32_t u = v.u;
  u = u + 0x7fffu + ((u >> 16) & 1u);
  return (unsigned short)(u >> 16);
}
__device__ __forceinline__ unsigned int cvtpk(float lo, float hi) {
  unsigned int r;
  asm("v_cvt_pk_bf16_f32 %0, %1, %2" : "=v"(r) : "v"(lo), "v"(hi));
  return r;
}
__device__ __forceinline__ void gload16(const void* g, void* lds) {
  __builtin_amdgcn_global_load_lds((const __attribute__((address_space(1))) void*)g,
                                   (__attribute__((address_space(3))) void*)lds, 16, 0, 0);
}

// ---------------- fused prep: x f32->bf16 | WqkvT (Q-scaled) | WprojT ----------------
// 1D grid 8192: [0,4096) cvt, [4096,7168) Wqkv transpose, [7168,8192) Wproj transpose.
__global__ __launch_bounds__(256) void prep(const float* __restrict__ x,
                                            unsigned short* __restrict__ xb,
                                            const float* __restrict__ Wq,
                                            unsigned short* __restrict__ WqT,
                                            const float* __restrict__ Wp,
                                            unsigned short* __restrict__ WpT) {
  const int id = blockIdx.x;
  const int t = threadIdx.x;
  if (id < 4096) {
    int i = id * 1024 + t * 4;
    float4 v = *(const float4*)(x + i);
    ushort4 o;
    o.x = f2b(v.x); o.y = f2b(v.y); o.z = f2b(v.z); o.w = f2b(v.w);
    *(ushort4*)(xb + i) = o;
    return;
  }
  __shared__ float tile[32][33];
  const float* W; unsigned short* Wt; int N; float scale; int scaleRows; int bi;
  if (id < 7168) { W = Wq; Wt = WqT; N = 3072; scale = QSCALE; scaleRows = 1024; bi = id - 4096; }
  else           { W = Wp; Wt = WpT; N = 1024; scale = 1.0f;   scaleRows = 0;    bi = id - 7168; }
  const int K = 1024;
  const int nbx = N / 32;
  const int x0 = (bi % nbx) * 32, y0 = (bi / nbx) * 32;
  const int tx = t & 31, ty = t >> 5;
  #pragma unroll
  for (int j = 0; j < 4; ++j)
    tile[ty + j * 8][tx] = W[(size_t)(y0 + ty + j * 8) * N + x0 + tx];
  __syncthreads();
  #pragma unroll
  for (int j = 0; j < 4; ++j) {
    int orow = x0 + ty + j * 8;
    float s = (orow < scaleRows) ? scale : 1.0f;
    Wt[(size_t)orow * K + y0 + tx] = f2b(tile[tx][ty + j * 8] * s);
  }
}

// ---------------- GEMM: C[M][N] = A[M][K] * Bt[N][K]^T + bias (unchanged r8) ----------
template<bool OUTF32, int BN>
__global__ __launch_bounds__(256, 3) void gemm_bt(const unsigned short* __restrict__ A,
                                                  const unsigned short* __restrict__ Bt,
                                                  const float* __restrict__ bias,
                                                  void* __restrict__ outp,
                                                  unsigned short* __restrict__ vtOut,
                                                  int M, int N, int K,
                                                  float bscale, int bscaleN, int mtiles) {
  constexpr int FN = BN / 32;
  constexpr int BH = BN / 2;
  __shared__ unsigned short As[2][64 * 64];
  __shared__ unsigned short Bs[2][BH * 64];
  const int t = threadIdx.x;
  const int lane = t & 63;
  const int w = t >> 6;
  const int wm = w >> 1, wn = w & 1;

  const int cpx = gridDim.x >> 3;
  const int swz = (blockIdx.x & 7) * cpx + (blockIdx.x >> 3);
  const int m0 = (swz % mtiles) * 128;
  const int n0 = (swz / mtiles) * BN;

  const f32x4 zero = {0.f, 0.f, 0.f, 0.f};
  f32x4 acc[4][FN];
  #pragma unroll
  for (int i = 0; i < 4; ++i)
    #pragma unroll
    for (int j = 0; j < FN; ++j) acc[i][j] = zero;

  const int cl = lane & 15, g = lane >> 4;
  const int prow = t >> 3;
  const int pc   = (t & 7) ^ (prow & 7);

  auto stage = [&](int k0, int buf) {
    #pragma unroll
    for (int r = 0; r < 2; ++r) {
      int lrow = r * 32 + prow + 64 * (pc >> 2);
      gload16(A + (size_t)(m0 + lrow) * K + k0 + (pc & 3) * 8,
              (char*)As[buf] + r * 4096 + t * 16);
    }
    #pragma unroll
    for (int r = 0; r < BN / 64; ++r) {
      int lrow = r * 32 + prow + BH * (pc >> 2);
      gload16(Bt + (size_t)(n0 + lrow) * K + k0 + (pc & 3) * 8,
              (char*)Bs[buf] + r * 4096 + t * 16);
    }
  };

  stage(0, 0);
  __syncthreads();

  const int nk = K >> 5;
  for (int ki = 0; ki < nk; ++ki) {
    const int cur = ki & 1;
    if (ki + 1 < nk) stage((ki + 1) << 5, cur ^ 1);
    char* AsB = (char*)As[cur];
    char* BsB = (char*)Bs[cur];
    short8 af[4], bfr[FN];
    #pragma unroll
    for (int f = 0; f < 4; ++f) {
      int pr = f * 16 + cl;
      af[f] = *(const short8*)(AsB + pr * 128 + ((((wm << 2) + g) ^ (pr & 7)) << 4));
    }
    #pragma unroll
    for (int f = 0; f < FN; ++f) {
      int lr = wn * BH + f * 16 + cl;
      int pr = lr & (BH - 1);
      bfr[f] = *(const short8*)(BsB + pr * 128 + ((((wn << 2) + g) ^ (pr & 7)) << 4));
    }
    #pragma unroll
    for (int fm = 0; fm < 4; ++fm)
      #pragma unroll
      for (int fn = 0; fn < FN; ++fn)
        acc[fm][fn] = __builtin_amdgcn_mfma_f32_16x16x32_bf16(af[fm], bfr[fn], acc[fm][fn], 0, 0, 0);
    __syncthreads();
  }

  const bool vpath = (!OUTF32) && (vtOut != nullptr) && (n0 >= 2048);
  #pragma unroll
  for (int fn = 0; fn < FN; ++fn) {
    int col = n0 + wn * BH + fn * 16 + cl;
    float bv = bias[col] * ((col < bscaleN) ? bscale : 1.0f);
    if (vpath) {
      int hcol = col - 2048;
      size_t vrow = (size_t)hcol * 2048;
      #pragma unroll
      for (int fm = 0; fm < 4; ++fm) {
        int rbase = m0 + wm * 64 + fm * 16 + g * 4;
        int b = rbase >> 11, s = rbase & 2047;
        ushort4 ov;
        ov.x = f2b(acc[fm][fn][0] + bv);
        ov.y = f2b(acc[fm][fn][1] + bv);
        ov.z = f2b(acc[fm][fn][2] + bv);
        ov.w = f2b(acc[fm][fn][3] + bv);
        *(ushort4*)(vtOut + (size_t)b * 1024 * 2048 + vrow + s) = ov;
      }
    } else {
      #pragma unroll
      for (int fm = 0; fm < 4; ++fm) {
        int rbase = m0 + wm * 64 + fm * 16 + g * 4;
        #pragma unroll
        for (int r = 0; r < 4; ++r) {
          float vout = acc[fm][fn][r] + bv;
          if (OUTF32) ((float*)outp)[(size_t)(rbase + r) * N + col] = vout;
          else ((unsigned short*)outp)[(size_t)(rbase + r) * N + col] = f2b(vout);
        }
      }
    }
  }
}

// ---------------- MFMA causal flash attention v7 ----------------
// v5 structure with the r8-PROVEN Ps LDS roundtrip for P^T -> B-frag
// (in-register shuffle version was wrong AND more LDS-unit ops: 16 bpermutes
// vs 6 ds ops — see r9 post-mortem). Ones A-frag in registers; LDS = 40KB
// (Ks16+Vs16+Ps8) -> exactly 4 blocks/CU.
__global__ __launch_bounds__(256, 4) void attn_mfma3(const unsigned short* __restrict__ qkv,
                                                     const unsigned short* __restrict__ Vt,
                                                     unsigned short* __restrict__ ctx) {
  const int idx = blockIdx.x;
  const int bh = ((idx & 7) << 2) | ((idx >> 3) & 3);
  const int qt = 31 - (idx >> 5);
  const int b = bh >> 4, h = bh & 15;
  const int t = threadIdx.x;
  const int l = t & 63;
  const int w = t >> 6;
  const int cl = l & 15;
  const int g  = l >> 4;

  __shared__ unsigned short Ks[2][64 * 64];
  __shared__ unsigned short Vs[2][64 * 64];
  __shared__ unsigned short Ps[4][16 * 64];

  char* Pbuf = (char*)(&Ps[w][0]);

  const size_t kbase  = (size_t)(b * 2048) * 3072 + 1024 + h * 64;
  const size_t vtbase = (size_t)(bh * 64) * 2048;

  auto stage = [&](int jt, int buf) {
    #pragma unroll
    for (int i = 0; i < 2; ++i) {
      int row = i * 32 + w * 8 + (l >> 3);
      int ch  = (l & 7) ^ (l >> 3);
      gload16(qkv + kbase + (size_t)(jt * 64 + row) * 3072 + ch * 8,
              (char*)Ks[buf] + i * 4096 + w * 1024);
      gload16(Vt + vtbase + (size_t)row * 2048 + jt * 64 + ch * 8,
              (char*)Vs[buf] + i * 4096 + w * 1024);
    }
  };

  stage(0, 0);
  __syncthreads();

  // ones-row A-frag in registers: A[row=cl][k], row0 = 1.0
  short8 a5;
  {
    short hv = (cl == 0) ? (short)0x3F80 : (short)0;
    #pragma unroll
    for (int j = 0; j < 8; ++j) a5[j] = hv;
  }

  // Q fragment (pre-scaled by QSCALE), B-layout: col=q=cl, k=d
  short8 bq[2];
  {
    const unsigned short* qp = qkv + (size_t)(b * 2048 + qt * 64 + w * 16 + cl) * 3072 + h * 64 + g * 8;
    bq[0] = *(const short8*)(qp);
    bq[1] = *(const short8*)(qp + 32);
  }

  f32x4 o[4], o5;
  #pragma unroll
  for (int c = 0; c < 4; ++c) o[c] = (f32x4){0.f, 0.f, 0.f, 0.f};
  o5 = (f32x4){0.f, 0.f, 0.f, 0.f};
  float m = -1e30f;

  for (int jt = 0; jt <= qt; ++jt) {
    const int cur = jt & 1;
    if (jt < qt) stage(jt + 1, cur ^ 1);
    char* KsB = (char*)Ks[cur];
    char* VsB = (char*)Vs[cur];

    short8 ak[4][2];
    #pragma unroll
    for (int tt = 0; tt < 4; ++tt)
      #pragma unroll
      for (int kk = 0; kk < 2; ++kk)
        ak[tt][kk] = *(const short8*)(KsB + (((tt * 16 + cl) * 128 + kk * 64 + g * 16) ^ ((cl & 7) << 4)));
    short8 av[4][2];
    #pragma unroll
    for (int c = 0; c < 4; ++c)
      #pragma unroll
      for (int kk = 0; kk < 2; ++kk)
        av[c][kk] = *(const short8*)(VsB + (((c * 16 + cl) * 128 + kk * 64 + g * 16) ^ ((cl & 7) << 4)));

    // ---- QK^T ----
    f32x4 st[4];
    #pragma unroll
    for (int tt = 0; tt < 4; ++tt) st[tt] = (f32x4){0.f, 0.f, 0.f, 0.f};
    __builtin_amdgcn_s_setprio(1);
    #pragma unroll
    for (int kk = 0; kk < 2; ++kk)
      #pragma unroll
      for (int tt = 0; tt < 4; ++tt)
        st[tt] = __builtin_amdgcn_mfma_f32_16x16x32_bf16(ak[tt][kk], bq[kk], st[tt], 0, 0, 0);
    __builtin_amdgcn_s_setprio(0);

    // ---- softmax (z in exp2 domain; kv_loc = tt*16+4g+r, q row = cl) ----
    float z[4][4];
    #pragma unroll
    for (int tt = 0; tt < 4; ++tt)
      #pragma unroll
      for (int r = 0; r < 4; ++r) z[tt][r] = st[tt][r];
    if (jt == qt) {
      int q_loc = w * 16 + cl;
      #pragma unroll
      for (int tt = 0; tt < 4; ++tt)
        #pragma unroll
        for (int r = 0; r < 4; ++r)
          if (tt * 16 + 4 * g + r > q_loc) z[tt][r] = -1e30f;
    }
    float m0a = fmaxf(fmaxf(z[0][0], z[0][1]), fmaxf(z[0][2], z[0][3]));
    float m1a = fmaxf(fmaxf(z[1][0], z[1][1]), fmaxf(z[1][2], z[1][3]));
    float m2a = fmaxf(fmaxf(z[2][0], z[2][1]), fmaxf(z[2][2], z[2][3]));
    float m3a = fmaxf(fmaxf(z[3][0], z[3][1]), fmaxf(z[3][2], z[3][3]));
    float cm = fmaxf(fmaxf(m0a, m1a), fmaxf(m2a, m3a));
    cm = fmaxf(cm, __shfl_xor(cm, 16));
    cm = fmaxf(cm, __shfl_xor(cm, 32));

    if (!__all(cm <= m + 8.f)) {           // defer-max THR=8
      float mn = fmaxf(m, cm);
      float alpha = exp2f(m - mn);
      m = mn;
      #pragma unroll
      for (int c = 0; c < 4; ++c)
        #pragma unroll
        for (int r = 0; r < 4; ++r) o[c][r] *= alpha;
      o5[0] *= alpha;
    }

    // ---- P -> bf16, through per-wave Ps LDS (proven r8 path) ----
    #pragma unroll
    for (int tt = 0; tt < 4; ++tt) {
      float p0 = exp2f(z[tt][0] - m), p1 = exp2f(z[tt][1] - m);
      float p2 = exp2f(z[tt][2] - m), p3 = exp2f(z[tt][3] - m);
      uint2 val;
      val.x = cvtpk(p0, p1);
      val.y = cvtpk(p2, p3);
      *(uint2*)(Pbuf + ((cl * 128 + tt * 32 + g * 8) ^ ((cl & 7) << 4))) = val;
    }
    short8 bp[2];
    #pragma unroll
    for (int kk = 0; kk < 2; ++kk)
      bp[kk] = *(const short8*)(Pbuf + ((cl * 128 + kk * 64 + g * 16) ^ ((cl & 7) << 4)));

    // ---- PV (+ ones-row for l) ----
    __builtin_amdgcn_s_setprio(1);
    #pragma unroll
    for (int kk = 0; kk < 2; ++kk) {
      #pragma unroll
      for (int c = 0; c < 4; ++c)
        o[c] = __builtin_amdgcn_mfma_f32_16x16x32_bf16(av[c][kk], bp[kk], o[c], 0, 0, 0);
      o5 = __builtin_amdgcn_mfma_f32_16x16x32_bf16(a5, bp[kk], o5, 0, 0, 0);
    }
    __builtin_amdgcn_s_setprio(0);

    __syncthreads();   // drains prefetch (latency hidden) + rw sync
  }

  // epilogue: lane holds O^T[d=c*16+4g+r][q=cl]; l lives in o5[0] on g==0 lanes
  float lsum = __shfl(o5[0], cl);
  float inv = 1.f / lsum;
  unsigned short* crow = ctx + (size_t)(b * 2048 + qt * 64 + w * 16 + cl) * 1024 + h * 64 + g * 4;
  #pragma unroll
  for (int c = 0; c < 4; ++c) {
    uint2 val;
    val.x = cvtpk(o[c][0] * inv, o[c][1] * inv);
    val.y = cvtpk(o[c][2] * inv, o[c][3] * inv);
    *(uint2*)(crow + c * 16) = val;
  }
}

// ---------------- launch ----------------
extern "C" void kernel_launch(void* const* d_in, const int* in_sizes, int n_in,
                              void* d_out, int out_size, void* d_ws, size_t ws_size,
                              hipStream_t stream) {
  const float* x     = (const float*)d_in[0];   // [2,2048,1024]
  const float* Wqkv  = (const float*)d_in[1];   // [1024,3072]
  const float* bqkv  = (const float*)d_in[2];   // [3072]
  const float* Wproj = (const float*)d_in[3];   // [1024,1024]
  const float* bproj = (const float*)d_in[4];   // [1024]
  float* out = (float*)d_out;

  char* ws = (char*)d_ws;
  unsigned short* xb     = (unsigned short*)(ws);                 //  8 MB [4096][1024]
  unsigned short* wqkvT  = (unsigned short*)(ws + 8388608);       //  6 MB [3072][1024]
  unsigned short* wprojT = (unsigned short*)(ws + 14680064);      //  2 MB [1024][1024]
  unsigned short* qkv    = (unsigned short*)(ws + 16777216);      // 24 MB [4096][3072] (V-part unused)
  unsigned short* ctx    = (unsigned short*)(ws + 41943040);      //  8 MB [4096][1024]
  unsigned short* vt     = (unsigned short*)(ws + 50331648);      //  8 MB [32][64][2048]

  prep<<<8192, 256, 0, stream>>>(x, xb, Wqkv, wqkvT, Wproj, wprojT);

  // qkv GEMM: grid 32x24 = 768 (1D, %8==0); V-columns written transposed into vt
  gemm_bt<false, 128><<<768, 256, 0, stream>>>(xb, wqkvT, bqkv, qkv, vt,
                                               4096, 3072, 1024, QSCALE, 1024, 32);

  attn_mfma3<<<1024, 256, 0, stream>>>(qkv, vt, ctx);

  // proj GEMM: 128x64 tiles, grid 32x16 = 512
  gemm_bt<true, 64><<<512, 256, 0, stream>>>(ctx, wprojT, bproj, out, nullptr,
                                             4096, 1024, 1024, 1.0f, 0, 32);
}